// Round 2
// baseline (94.872 us; speedup 1.0000x reference)
//
#include <hip/hip_runtime.h>

#define NB 8
#define TAPS 5

// antireflect column fetch: j in [-2, N+1]
__device__ __forceinline__ float ldc(const float* __restrict__ row, int j, int N) {
    if ((unsigned)j < (unsigned)N) return row[j];
    const int e  = (j < 0) ? 0 : (N - 1);
    const int rr = (j < 0) ? -j : (2 * (N - 1) - j);
    return 2.f * row[e] - row[rr];
}

// antireflect row+column fetch
__device__ __forceinline__ float ldrc(const float* __restrict__ plane, int m, int j, int N) {
    if ((unsigned)m < (unsigned)N) return ldc(plane + (size_t)m * N, j, N);
    const int e  = (m < 0) ? 0 : (N - 1);
    const int rm = (m < 0) ? -m : (2 * (N - 1) - m);
    return 2.f * ldc(plane + (size_t)e * N, j, N) - ldc(plane + (size_t)rm * N, j, N);
}

// Fused one-level 2D synthesis: block computes a TH x TW output tile.
// Phase 1: vertical synthesis (rows) -> LDS Sh/Dh [TH][TW/2+4] incl. col halo.
// Phase 2: horizontal synthesis from LDS -> out tile, float2 stores.
template<int TH, int TW>
__global__ __launch_bounds__(256)
void idwt_fused(const float* __restrict__ Ass, const float* __restrict__ Asd,
                const float* __restrict__ Ads, const float* __restrict__ Add,
                const float* __restrict__ h, const float* __restrict__ g,
                float* __restrict__ out, int N) {
    constexpr int TWc = TW / 2 + 4;   // coarse cols incl halo
    constexpr int THc = TH / 2;       // coarse rows per tile
    __shared__ float Sh[TH][TWc];
    __shared__ float Dh[TH][TWc];

    const int b  = blockIdx.z;
    const int r0 = blockIdx.y * TH;   // output row base
    const int w0 = blockIdx.x * TW;   // output col base
    const int n0 = r0 >> 1;           // coarse row base
    const int c0 = w0 >> 1;           // coarse col base
    const int tid = threadIdx.x;

    float hk[2][TAPS], gk[2][TAPS];   // hk[p][t] = h[8-2t+p] (flipped polyphase)
#pragma unroll
    for (int t = 0; t < TAPS; ++t) {
        hk[0][t] = h[8 - 2 * t]; hk[1][t] = h[9 - 2 * t];
        gk[0][t] = g[8 - 2 * t]; gk[1][t] = g[9 - 2 * t];
    }

    const size_t plane = (size_t)N * N;
    const float* pa = Ass + (size_t)b * plane;
    const float* pb = Asd + (size_t)b * plane;
    const float* pc = Ads + (size_t)b * plane;
    const float* pd = Add + (size_t)b * plane;

    // ---- phase 1: vertical synthesis into LDS (both polyphases per thread)
    for (int e = tid; e < THc * TWc; e += 256) {
        const int nl = e / TWc;
        const int cc = e - nl * TWc;
        const int n = n0 + nl;            // coarse row of this output row-pair
        const int j = c0 - 2 + cc;        // coarse col (with halo)
        float s0 = 0.f, s1 = 0.f, d0 = 0.f, d1 = 0.f;
#pragma unroll
        for (int t = 0; t < TAPS; ++t) {
            const int m = n + t - 2;
            const float va = ldrc(pa, m, j, N);
            const float vb = ldrc(pb, m, j, N);
            const float vc = ldrc(pc, m, j, N);
            const float vd = ldrc(pd, m, j, N);
            s0 += hk[0][t] * va + gk[0][t] * vb;
            s1 += hk[1][t] * va + gk[1][t] * vb;
            d0 += hk[0][t] * vc + gk[0][t] * vd;
            d1 += hk[1][t] * vc + gk[1][t] * vd;
        }
        Sh[2 * nl][cc] = s0; Sh[2 * nl + 1][cc] = s1;
        Dh[2 * nl][cc] = d0; Dh[2 * nl + 1][cc] = d1;
    }
    __syncthreads();

    // ---- phase 2: horizontal synthesis from LDS, write float2
    const int M = 2 * N;
    for (int e = tid; e < TH * (TW / 2); e += 256) {
        const int r  = e / (TW / 2);
        const int cl = e - r * (TW / 2);
        float o0 = 0.f, o1 = 0.f;
#pragma unroll
        for (int t = 0; t < TAPS; ++t) {
            const float sv = Sh[r][cl + t];
            const float dv = Dh[r][cl + t];
            o0 += hk[0][t] * sv + gk[0][t] * dv;
            o1 += hk[1][t] * sv + gk[1][t] * dv;
        }
        *reinterpret_cast<float2*>(out + ((size_t)b * M + (r0 + r)) * M + w0 + 2 * cl)
            = make_float2(o0, o1);
    }
}

extern "C" void kernel_launch(void* const* d_in, const int* in_sizes, int n_in,
                              void* d_out, int out_size, void* d_ws, size_t ws_size,
                              hipStream_t stream) {
    const float* ss = (const float*)d_in[0];
    const float* sd[3] = {(const float*)d_in[1], (const float*)d_in[2], (const float*)d_in[3]};
    const float* ds[3] = {(const float*)d_in[4], (const float*)d_in[5], (const float*)d_in[6]};
    const float* dd[3] = {(const float*)d_in[7], (const float*)d_in[8], (const float*)d_in[9]};
    const float* h = (const float*)d_in[10];
    const float* g = (const float*)d_in[11];
    float* out = (float*)d_out;

    // ws: I0 = level-2 output (8*256*256*4 = 2 MiB), I1 = level-1 output (8 MiB).
    // Distinct buffers: the fused kernel reads its input while writing its output.
    char* ws = (char*)d_ws;
    float* I0 = (float*)ws;
    float* I1 = (float*)(ws + ((size_t)2 << 20));

    // level 2: 128 -> 256
    {
        const int N = 128, M = 256;
        constexpr int TH = 16, TW = 32;
        dim3 grid(M / TW, M / TH, NB);
        idwt_fused<TH, TW><<<grid, 256, 0, stream>>>(ss, sd[2], ds[2], dd[2], h, g, I0, N);
    }
    // level 1: 256 -> 512
    {
        const int N = 256, M = 512;
        constexpr int TH = 32, TW = 64;
        dim3 grid(M / TW, M / TH, NB);
        idwt_fused<TH, TW><<<grid, 256, 0, stream>>>(I0, sd[1], ds[1], dd[1], h, g, I1, N);
    }
    // level 0: 512 -> 1024
    {
        const int N = 512, M = 1024;
        constexpr int TH = 32, TW = 64;
        dim3 grid(M / TW, M / TH, NB);
        idwt_fused<TH, TW><<<grid, 256, 0, stream>>>(I1, sd[0], ds[0], dd[0], h, g, out, N);
    }
}

// Round 3
// 62.780 us; speedup vs baseline: 1.5112x; 1.5112x over previous
//
#include <hip/hip_runtime.h>

#define NB 8
#define TAPS 5

// antireflect column fetch: j in [-2, N+1]
__device__ __forceinline__ float ldc(const float* __restrict__ row, int j, int N) {
    if ((unsigned)j < (unsigned)N) return row[j];
    const int e  = (j < 0) ? 0 : (N - 1);
    const int rr = (j < 0) ? -j : (2 * (N - 1) - j);
    return 2.f * row[e] - row[rr];
}

// antireflect row+column fetch
__device__ __forceinline__ float ldrc(const float* __restrict__ plane, int m, int j, int N) {
    if ((unsigned)m < (unsigned)N) return ldc(plane + (size_t)m * N, j, N);
    const int e  = (m < 0) ? 0 : (N - 1);
    const int rm = (m < 0) ? -m : (2 * (N - 1) - m);
    return 2.f * ldc(plane + (size_t)e * N, j, N) - ldc(plane + (size_t)rm * N, j, N);
}

// Fused one-level 2D synthesis with LDS input staging.
// Phase 0: stage 4 input-plane coarse tiles (incl. halo, antireflect applied) into LDS.
// Phase 1: vertical synthesis from LDS -> Sh/Dh.
// Phase 2: horizontal synthesis from Sh/Dh -> out tile (float4 stores).
template<int TH, int TW>
__global__ __launch_bounds__(256)
void idwt_fused(const float* __restrict__ Ass, const float* __restrict__ Asd,
                const float* __restrict__ Ads, const float* __restrict__ Add,
                const float* __restrict__ h, const float* __restrict__ g,
                float* __restrict__ out, int N) {
    constexpr int THc = TH / 2;       // coarse rows per tile
    constexpr int TWc = TW / 2 + 4;   // coarse cols incl col halo
    constexpr int RH  = THc + 4;      // coarse rows incl row halo
    __shared__ float Ain[4][RH][TWc];
    __shared__ float Sh[TH][TWc];
    __shared__ float Dh[TH][TWc];

    const int b  = blockIdx.z;
    const int r0 = blockIdx.y * TH;   // output row base
    const int w0 = blockIdx.x * TW;   // output col base
    const int n0 = r0 >> 1;           // coarse row base
    const int c0 = w0 >> 1;           // coarse col base
    const int tid = threadIdx.x;

    float hk[2][TAPS], gk[2][TAPS];   // hk[p][t] = h[8-2t+p] (flipped polyphase)
#pragma unroll
    for (int t = 0; t < TAPS; ++t) {
        hk[0][t] = h[8 - 2 * t]; hk[1][t] = h[9 - 2 * t];
        gk[0][t] = g[8 - 2 * t]; gk[1][t] = g[9 - 2 * t];
    }

    const size_t plane = (size_t)N * N;

    // ---- phase 0: stage inputs into LDS (each global element touched once)
#pragma unroll
    for (int q = 0; q < 4; ++q) {
        const float* __restrict__ p =
            (q == 0) ? Ass : (q == 1) ? Asd : (q == 2) ? Ads : Add;
        p += (size_t)b * plane;
        for (int e = tid; e < RH * TWc; e += 256) {
            const int rr = e / TWc;
            const int cc = e - rr * TWc;
            Ain[q][rr][cc] = ldrc(p, n0 - 2 + rr, c0 - 2 + cc, N);
        }
    }
    __syncthreads();

    // ---- phase 1: vertical synthesis from LDS
    for (int e = tid; e < THc * TWc; e += 256) {
        const int nl = e / TWc;
        const int cc = e - nl * TWc;
        float s0 = 0.f, s1 = 0.f, d0 = 0.f, d1 = 0.f;
#pragma unroll
        for (int t = 0; t < TAPS; ++t) {
            const float va = Ain[0][nl + t][cc];
            const float vb = Ain[1][nl + t][cc];
            const float vc = Ain[2][nl + t][cc];
            const float vd = Ain[3][nl + t][cc];
            s0 += hk[0][t] * va + gk[0][t] * vb;
            s1 += hk[1][t] * va + gk[1][t] * vb;
            d0 += hk[0][t] * vc + gk[0][t] * vd;
            d1 += hk[1][t] * vc + gk[1][t] * vd;
        }
        Sh[2 * nl][cc] = s0; Sh[2 * nl + 1][cc] = s1;
        Dh[2 * nl][cc] = d0; Dh[2 * nl + 1][cc] = d1;
    }
    __syncthreads();

    // ---- phase 2: horizontal synthesis from LDS, float4 stores (2 col-pairs/thread)
    const int M = 2 * N;
    constexpr int KW = TW / 4;        // float4 stores per row
    for (int e = tid; e < TH * KW; e += 256) {
        const int r  = e / KW;
        const int k  = e - r * KW;
        const int cl = 2 * k;
        float sv[TAPS + 1], dv[TAPS + 1];
#pragma unroll
        for (int t = 0; t < TAPS + 1; ++t) {
            sv[t] = Sh[r][cl + t];
            dv[t] = Dh[r][cl + t];
        }
        float4 o = make_float4(0.f, 0.f, 0.f, 0.f);
#pragma unroll
        for (int t = 0; t < TAPS; ++t) {
            o.x += hk[0][t] * sv[t]     + gk[0][t] * dv[t];
            o.y += hk[1][t] * sv[t]     + gk[1][t] * dv[t];
            o.z += hk[0][t] * sv[t + 1] + gk[0][t] * dv[t + 1];
            o.w += hk[1][t] * sv[t + 1] + gk[1][t] * dv[t + 1];
        }
        *reinterpret_cast<float4*>(out + ((size_t)b * M + (r0 + r)) * M + w0 + 4 * k) = o;
    }
}

extern "C" void kernel_launch(void* const* d_in, const int* in_sizes, int n_in,
                              void* d_out, int out_size, void* d_ws, size_t ws_size,
                              hipStream_t stream) {
    const float* ss = (const float*)d_in[0];
    const float* sd[3] = {(const float*)d_in[1], (const float*)d_in[2], (const float*)d_in[3]};
    const float* ds[3] = {(const float*)d_in[4], (const float*)d_in[5], (const float*)d_in[6]};
    const float* dd[3] = {(const float*)d_in[7], (const float*)d_in[8], (const float*)d_in[9]};
    const float* h = (const float*)d_in[10];
    const float* g = (const float*)d_in[11];
    float* out = (float*)d_out;

    // ws: I0 = level-2 output (2 MiB), I1 = level-1 output (8 MiB). Distinct
    // buffers: the fused kernel reads its input while writing its output.
    char* ws = (char*)d_ws;
    float* I0 = (float*)ws;
    float* I1 = (float*)(ws + ((size_t)2 << 20));

    // level 2: 128 -> 256
    {
        const int N = 128, M = 256;
        constexpr int TH = 16, TW = 32;
        dim3 grid(M / TW, M / TH, NB);
        idwt_fused<TH, TW><<<grid, 256, 0, stream>>>(ss, sd[2], ds[2], dd[2], h, g, I0, N);
    }
    // level 1: 256 -> 512
    {
        const int N = 256, M = 512;
        constexpr int TH = 32, TW = 64;
        dim3 grid(M / TW, M / TH, NB);
        idwt_fused<TH, TW><<<grid, 256, 0, stream>>>(I0, sd[1], ds[1], dd[1], h, g, I1, N);
    }
    // level 0: 512 -> 1024
    {
        const int N = 512, M = 1024;
        constexpr int TH = 32, TW = 64;
        dim3 grid(M / TW, M / TH, NB);
        idwt_fused<TH, TW><<<grid, 256, 0, stream>>>(I1, sd[0], ds[0], dd[0], h, g, out, N);
    }
}